// Round 1
// baseline (3683.743 us; speedup 1.0000x reference)
//
#include <hip/hip_runtime.h>
#include <math.h>

namespace {

constexpr int TOK = 4096;   // B*S
constexpr int DL  = 512;    // LATENT
constexpr int DS  = 128;    // SYM
constexpr int NC  = 512;    // NUM_CODES
constexpr int NSLOT = 13;   // slots ever READ: 0..12 (appends at t=3 are never read)

__device__ __forceinline__ float wsum(float v){
  #pragma unroll
  for(int o=32;o>0;o>>=1) v += __shfl_xor(v,o);
  return v;
}

// ---------------------------------------------------------------------------
// Generic fp32 GEMM:  C[m, 0..511] = sum_k Ahat[m,k] * What[n,k] (+ epilogue)
// C row stride hardcoded to 512 (all outputs are 512 wide).
// AMODE: 0 plain A (row stride lda)
//        1 concat [ A (cols<K0) | slab[rowsel[m]] (cols>=K0, latent row) ]
//        2 concat [ A (cols<K0) | cbrow[rowsel[m]] (cols>=K0, 128-wide row) ]
// WT:    1 -> W is [N,K] (we need W[n,k]);  0 -> W is [K,N] (B matrix, NN gemm)
// EPI:   0 +bias; 1 relu(+bias); 2 +bias + res[m,n]; 4 +bias + prompt[(m&255),n], dual-write C2
// ---------------------------------------------------------------------------
template<int AMODE,int WT,int EPI>
__global__ __launch_bounds__(256)
void gemm_k(const float* __restrict__ A, int lda,
            const float* __restrict__ W, int ldw,
            const float* __restrict__ bias,
            const float* __restrict__ res,
            const float* __restrict__ extra,
            const float* __restrict__ Ab,
            const int* __restrict__ rowsel,
            float* __restrict__ C, float* __restrict__ C2,
            int K, int K0)
{
  constexpr int BM=64, BN=128, BK=32, T=256;
  constexpr int AF4 = BM*BK/4/T;  // 2 float4 per thread
  constexpr int WF4 = BN*BK/4/T;  // 4 float4 per thread
  __shared__ float As[BK][BM+4];  // stride 68 floats: 16B-aligned rows, <=4-way store conflicts
  __shared__ float Ws[BK][BN+4];  // stride 132
  const int tid = threadIdx.x;
  const int m0 = blockIdx.x*BM, n0 = blockIdx.y*BN;
  const int ty = tid>>4, tx = tid&15;   // ty: 16 row groups of 4; tx: 16 col groups (4 + 4@+64)

  float4 pa[AF4], pw[WF4];

  auto loadA = [&](int k0){
    #pragma unroll
    for(int it=0; it<AF4; ++it){
      int v = tid + T*it;
      int r = v>>3, c4 = v&7;
      int gr = m0 + r, gc = k0 + (c4<<2);
      const float* src;
      if(AMODE==0)        src = A + (size_t)gr*lda + gc;
      else if(gc < K0)    src = A + (size_t)gr*lda + gc;
      else if(AMODE==1)   src = Ab + ((size_t)rowsel[gr]<<21) + ((size_t)gr<<9) + (gc-K0);
      else                src = Ab + ((size_t)rowsel[gr]<<7) + (gc-K0);
      pa[it] = *(const float4*)src;
    }
  };
  auto loadW = [&](int k0){
    #pragma unroll
    for(int it=0; it<WF4; ++it){
      int v = tid + T*it;
      if(WT==1){
        int r = v>>3, c4 = v&7;
        pw[it] = *(const float4*)(W + (size_t)(n0+r)*ldw + k0 + (c4<<2));
      } else {
        int r = v>>5, c4 = v&31;
        pw[it] = *(const float4*)(W + (size_t)(k0+r)*ldw + n0 + (c4<<2));
      }
    }
  };

  float acc[4][8];
  #pragma unroll
  for(int i=0;i<4;i++)
    #pragma unroll
    for(int j=0;j<8;j++) acc[i][j]=0.f;

  loadA(0); loadW(0);
  for(int k0=0; k0<K; k0+=BK){
    __syncthreads();
    #pragma unroll
    for(int it=0; it<AF4; ++it){
      int v = tid + T*it; int r=v>>3, c4=v&7;
      As[(c4<<2)+0][r]=pa[it].x; As[(c4<<2)+1][r]=pa[it].y;
      As[(c4<<2)+2][r]=pa[it].z; As[(c4<<2)+3][r]=pa[it].w;
    }
    #pragma unroll
    for(int it=0; it<WF4; ++it){
      int v = tid + T*it;
      if(WT==1){
        int r=v>>3, c4=v&7;
        Ws[(c4<<2)+0][r]=pw[it].x; Ws[(c4<<2)+1][r]=pw[it].y;
        Ws[(c4<<2)+2][r]=pw[it].z; Ws[(c4<<2)+3][r]=pw[it].w;
      } else {
        int r=v>>5, c4=v&31;
        *(float4*)&Ws[r][c4<<2] = pw[it];
      }
    }
    __syncthreads();
    if(k0+BK < K){ loadA(k0+BK); loadW(k0+BK); }
    #pragma unroll
    for(int kk=0; kk<BK; kk++){
      float4 a4 = *(const float4*)&As[kk][ty<<2];
      float4 b0 = *(const float4*)&Ws[kk][tx<<2];
      float4 b1 = *(const float4*)&Ws[kk][64+(tx<<2)];
      float a[4]={a4.x,a4.y,a4.z,a4.w};
      float b[8]={b0.x,b0.y,b0.z,b0.w,b1.x,b1.y,b1.z,b1.w};
      #pragma unroll
      for(int i=0;i<4;i++)
        #pragma unroll
        for(int j=0;j<8;j++)
          acc[i][j] = fmaf(a[i], b[j], acc[i][j]);
    }
  }
  #pragma unroll
  for(int i=0;i<4;i++){
    int m = m0 + (ty<<2) + i;
    float v0[4], v1[4];
    #pragma unroll
    for(int j=0;j<8;j++){
      int n = n0 + ((j<4)? (tx<<2)+j : 64+(tx<<2)+(j-4));
      float v = acc[i][j];
      if(bias) v += bias[n];
      if(EPI==1) v = fmaxf(v,0.f);
      if(EPI==2) v += res[((size_t)m<<9)+n];
      if(EPI==4) v += extra[((size_t)(m&255)<<9)+n];
      if(j<4) v0[j]=v; else v1[j-4]=v;
    }
    *(float4*)&C[((size_t)m<<9) + n0 + (tx<<2)]      = make_float4(v0[0],v0[1],v0[2],v0[3]);
    *(float4*)&C[((size_t)m<<9) + n0 + 64 + (tx<<2)] = make_float4(v1[0],v1[1],v1[2],v1[3]);
    if(EPI==4){
      *(float4*)&C2[((size_t)m<<9) + n0 + (tx<<2)]      = make_float4(v0[0],v0[1],v0[2],v0[3]);
      *(float4*)&C2[((size_t)m<<9) + n0 + 64 + (tx<<2)] = make_float4(v1[0],v1[1],v1[2],v1[3]);
    }
  }
}

// --- init: active=1, msg_mask={1,0,...}, relcache slot0 = qry_b (sym=0) ---
__global__ void init_k(int* __restrict__ msg, int* __restrict__ act,
                       float* __restrict__ relc, const float* __restrict__ qb){
  int i = blockIdx.x*256 + threadIdx.x;
  if(i < TOK){
    act[i] = 1;
    #pragma unroll
    for(int nn=0;nn<4;nn++) relc[nn*TOK + i] = qb[nn];
  }
  if(i < 32) msg[i] = (i==0) ? 1 : 0;
}

// --- combined quantizer bias: b2[n*512+c] = sym_b[n]·cb[n,c] - 0.5*|cb[n,c]|^2 ---
__global__ void bias2_k(const float* __restrict__ cb, const float* __restrict__ sb,
                        float* __restrict__ b2){
  int row = blockIdx.x*4 + (threadIdx.x>>6);   // 0..2047 = n*512+c
  int lane = threadIdx.x&63;
  const float* cv = cb + ((size_t)row<<7);
  const float* sbn = sb + ((row>>9)<<7);
  float c0=cv[lane], c1=cv[lane+64];
  float nrm = c0*c0 + c1*c1;
  float dt  = c0*sbn[lane] + c1*sbn[lane+64];
  nrm = wsum(nrm); dt = wsum(dt);
  if(lane==0) b2[row] = dt - 0.5f*nrm;
}

__global__ void snap_k(const int* __restrict__ msg, int* __restrict__ snap,
                       int* __restrict__ cons, int pt){
  int i = threadIdx.x;
  if(i<32){ snap[i] = (msg[i] && (i<pt)) ? 1:0; cons[i]=0; }
}
__global__ void mask_k(int* __restrict__ msg, const int* __restrict__ cons, int pe){
  int i = threadIdx.x;
  if(i<32) msg[i] = ((i<pe) && !cons[i]) ? 1:0;
}

// --- per-token argmax over snapshot-active slots (first-max tie-break) ---
__global__ void relmax_k(const float* __restrict__ relc, const int* __restrict__ snap,
                         int pt, int node, int* __restrict__ top, int* __restrict__ cons){
  int tok = blockIdx.x*256 + threadIdx.x;
  float best = -1e9f; int bs = 0;
  for(int s=0;s<pt;s++){
    float v = snap[s] ? relc[(size_t)((s<<2)+node)*TOK + tok] : -1e9f;
    if(v > best){ best = v; bs = s; }
  }
  top[tok] = bs;
  cons[bs] = 1;   // benign race: all writers store 1
}

// --- per-row argmax over 512 code scores (== argmin d2), first-index ties ---
__global__ void codemax_k(const float* __restrict__ sc, int* __restrict__ idx){
  int m = blockIdx.x*4 + (threadIdx.x>>6);
  int lane = threadIdx.x&63;
  const float* row = sc + ((size_t)m<<9);
  float best = -INFINITY; int bi = 0;
  #pragma unroll
  for(int r=0;r<8;r++){
    int c = lane + (r<<6);
    float v = row[c];
    if(v > best){ best=v; bi=c; }
  }
  #pragma unroll
  for(int o=32;o>0;o>>=1){
    float ov = __shfl_xor(best,o);
    int   oi = __shfl_xor(bi,o);
    if(ov > best || (ov==best && oi<bi)){ best=ov; bi=oi; }
  }
  if(lane==0) idx[m]=bi;
}

// --- halting/update/append: one wave per token row ---
__global__ void update_k(const float* __restrict__ no_, float* __restrict__ out,
                         float* __restrict__ slab, float* __restrict__ relc,
                         const int* __restrict__ idx, const float* __restrict__ cbn,
                         const float* __restrict__ qw, const float* __restrict__ qb,
                         int* __restrict__ act, int t, int ptr){
  int m = blockIdx.x*4 + (threadIdx.x>>6);
  int lane = threadIdx.x&63;
  const float* nrow = no_ + ((size_t)m<<9);
  float* orow = out + ((size_t)m<<9);
  float nv[8], ov[8]; float s=0.f;
  #pragma unroll
  for(int r=0;r<8;r++){
    int c = lane + (r<<6);
    nv[r]=nrow[c]; ov[r]=orow[c];
    float d = nv[r]-ov[r]; s += d*d;
  }
  s = wsum(s);                       // prev_out == out at delta time
  float delta = sqrtf(s);
  int a = act[m];
  int halt = (delta < 1e-3f) && a;
  int assigned = (t>0) ? a : 1;
  int upd = assigned && !halt;
  if(lane==0) act[m] = a && !halt;
  if(upd){
    #pragma unroll
    for(int r=0;r<8;r++) orow[lane+(r<<6)] = nv[r];
  }
  if(ptr >= 0){                      // append raw node_out + cached rel for all 4 nodes
    float* srow = slab + (((size_t)ptr)<<21) + ((size_t)m<<9);
    #pragma unroll
    for(int r=0;r<8;r++) srow[lane+(r<<6)] = nv[r];
    const float* q = cbn + ((size_t)idx[m]<<7);
    float q0=q[lane], q1=q[lane+64];
    #pragma unroll
    for(int nn=0;nn<4;nn++){
      float p = q0*qw[(nn<<7)+lane] + q1*qw[(nn<<7)+64+lane];
      p = wsum(p);
      if(lane==0) relc[(size_t)((ptr<<2)+nn)*TOK + m] = p + qb[nn];
    }
  }
}

} // namespace

extern "C" void kernel_launch(void* const* d_in, const int* in_sizes, int n_in,
                              void* d_out, int out_size, void* d_ws, size_t ws_size,
                              hipStream_t stream)
{
  (void)in_sizes; (void)n_in; (void)out_size; (void)ws_size;
  const float* x   = (const float*)d_in[0];
  const float* ipw = (const float*)d_in[1];
  const float* ipb = (const float*)d_in[2];
  const float* tp  = (const float*)d_in[3];
  const float* sw  = (const float*)d_in[4];
  const float* sb  = (const float*)d_in[5];
  const float* qw  = (const float*)d_in[6];
  const float* qb  = (const float*)d_in[7];
  const float* rw  = (const float*)d_in[8];
  const float* rb  = (const float*)d_in[9];
  const float* c1w = (const float*)d_in[10];
  const float* c1b = (const float*)d_in[11];
  const float* c2w = (const float*)d_in[12];
  const float* c2b = (const float*)d_in[13];
  const float* cb  = (const float*)d_in[14];
  float* out = (float*)d_out;
  float* ws  = (float*)d_ws;

  // workspace layout (floats); total ~141 MiB
  float* slab  = ws;                                   // 13 * 4096 * 512
  float* zread = slab  + (size_t)NSLOT*TOK*DL;
  float* hid   = zread + (size_t)TOK*DL;
  float* nodeo = hid   + (size_t)TOK*DL;
  float* score = nodeo + (size_t)TOK*DL;
  float* wcomb = score + (size_t)TOK*NC;               // 4 * 512 * 512
  float* b2    = wcomb + (size_t)4*NC*DL;              // 4 * 512
  float* relc  = b2    + (size_t)4*NC;                 // 13 * 4 * 4096
  int* top  = (int*)(relc + (size_t)NSLOT*4*TOK);
  int* idx  = top + TOK;
  int* act  = idx + TOK;
  int* msg  = act + TOK;
  int* cons = msg + 32;
  int* snap = cons + 32;

  dim3 G(TOK/64, 4), B(256);

  init_k<<<16,256,0,stream>>>(msg, act, relc, qb);
  bias2_k<<<512,256,0,stream>>>(cb, sb, b2);
  // Wcomb[n] = cb[n] @ sym_w[n]  (NN gemm, 512x512x128)
  for(int n=0;n<4;n++)
    gemm_k<0,0,0><<<dim3(8,4),B,0,stream>>>(cb + (size_t)n*NC*DS, DS,
        sw + (size_t)n*DS*DL, DL, nullptr, nullptr, nullptr, nullptr, nullptr,
        wcomb + (size_t)n*NC*DL, nullptr, DS, DL);
  // input projection + prompts -> out, and slab[0]
  gemm_k<0,1,4><<<G,B,0,stream>>>(x, DL, ipw, DL, ipb, nullptr, tp, nullptr, nullptr,
        out, slab, DL, DL);

  int ptr = 1;
  for(int t=0;t<4;t++){
    int pt = ptr;                                   // snapshot ptr for this op
    snap_k<<<1,64,0,stream>>>(msg, snap, cons, pt);
    for(int n=0;n<4;n++){
      relmax_k<<<16,256,0,stream>>>(relc, snap, pt, n, top, cons);
      // z_read = [out | slab[top]] @ read_w^T + read_b
      gemm_k<1,1,0><<<G,B,0,stream>>>(out, DL, rw + (size_t)n*DL*2*DL, 2*DL,
          rb + (size_t)n*DL, nullptr, nullptr, slab, top, zread, nullptr, 2*DL, DL);
      // scores = z_read @ Wcomb^T + b2   (== argmin d2 objective)
      gemm_k<0,1,0><<<G,B,0,stream>>>(zread, DL, wcomb + (size_t)n*NC*DL, DL,
          b2 + n*NC, nullptr, nullptr, nullptr, nullptr, score, nullptr, DL, DL);
      codemax_k<<<1024,256,0,stream>>>(score, idx);
      // hid = relu([z_read | cb[idx]] @ c1_w^T + c1_b)
      gemm_k<2,1,1><<<G,B,0,stream>>>(zread, DL, c1w + (size_t)n*DL*(DL+DS), DL+DS,
          c1b + (size_t)n*DL, nullptr, nullptr, cb + (size_t)n*NC*DS, idx, hid, nullptr, DL+DS, DL);
      // node_out = hid @ c2_w^T + c2_b + out
      gemm_k<0,1,2><<<G,B,0,stream>>>(hid, DL, c2w + (size_t)n*DL*DL, DL,
          c2b + (size_t)n*DL, out, nullptr, nullptr, nullptr, nodeo, nullptr, DL, DL);
      // halting / selective update / bus append (+rel cache); skip appends at t=3 (never read)
      update_k<<<1024,256,0,stream>>>(nodeo, out, slab, relc, idx,
          cb + (size_t)n*NC*DS, qw, qb, act, t, (t<3)? ptr : -1);
      ptr++;
    }
    if(t<3) mask_k<<<1,64,0,stream>>>(msg, cons, ptr);
  }
}

// Round 2
// 1491.667 us; speedup vs baseline: 2.4695x; 2.4695x over previous
//
#include <hip/hip_runtime.h>
#include <math.h>

namespace {

typedef _Float16 f16;
typedef __attribute__((ext_vector_type(8))) _Float16 f16x8;
typedef __attribute__((ext_vector_type(4))) float f32x4;

constexpr int TOK = 4096;
constexpr int DL  = 512;
constexpr int DS  = 128;
constexpr int NC  = 512;
constexpr int NSLOT = 13;

__device__ __forceinline__ float wsum(float v){
  #pragma unroll
  for(int o=32;o>0;o>>=1) v += __shfl_xor(v,o);
  return v;
}

__device__ __forceinline__ void gload16(const void* g, void* l){
  __builtin_amdgcn_global_load_lds(
      (const __attribute__((address_space(1))) unsigned int*)g,
      (__attribute__((address_space(3))) unsigned int*)l, 16, 0, 0);
}

// byte offset of the 16B slot holding (row, 16B-granule g) — bank-spread bijection
__device__ __forceinline__ int slotb(int row, int g){
  return (((row ^ ((row>>2)&1))<<2) | (g ^ (row&3))) << 4;
}

// ===========================================================================
// fp16x2-split MFMA GEMM.  C[m,0..511] = A[m,:K] * W[n,:K]^T (+ epilogue)
// A part1: hi/lo planes, row stride 512.  Part2 (cols >= K0):
//   AMODE 0: none (K0==K)   AMODE 1: slab[gidx[m]] (stride: slot<<21 + m<<9)
//   AMODE 2: codebook row gidx[m] (stride 128)
// B: hi/lo planes [512][K].
// EPI: 0 zread (bias, write hi/lo planes) ; 1 score (bias, write fp32)
//      2 hid   (bias+relu, hi/lo planes)  ; 3 nodeo (bias+res, fp32)
//      4 input (bias+prompt, fp32 + hi/lo + slab0 hi/lo)
// grid (64,4), 256 threads (4 waves of 64x32 output each)
// ===========================================================================
template<int AMODE,int EPI>
__global__ __launch_bounds__(256) void mgemm(
    const f16* __restrict__ A1h, const f16* __restrict__ A1l,
    const f16* __restrict__ A2h, const f16* __restrict__ A2l,
    const int* __restrict__ gidx,
    const f16* __restrict__ Bh, const f16* __restrict__ Bl,
    const float* __restrict__ bias, const float* __restrict__ res,
    float* __restrict__ Cf, f16* __restrict__ Ch, f16* __restrict__ Cl,
    f16* __restrict__ C2h, f16* __restrict__ C2l,
    int K, int K0)
{
  __shared__ __align__(16) char smem[2*24576];  // {Ah4K|Al4K|Bh8K|Bl8K} x2
  const int tid = threadIdx.x, w = tid>>6, l = tid&63;
  const int m0 = blockIdx.x*64, n0 = blockIdx.y*128;
  const int NK = K>>5, SW = K0>>5;

  // staging: 24 chunks of 1KB per K-step; wave w owns chunks [6w, 6w+6)
  const f16* sp[6]; const f16* sp2[6]; int loff[6];
  #pragma unroll
  for(int i=0;i<6;i++){
    int c = 6*w+i;
    int reg = (c>=16)?3:(c>=8)?2:(c>=4)?1:0;
    int cidx = c - ((reg==3)?16:(reg==2)?8:(reg==1)?4:0);
    int s = (cidx<<6) + l;
    int rp = s>>2, row = rp ^ ((rp>>2)&1), g = (s&3) ^ (row&3);
    loff[i] = ((reg==0)?0:(reg==1)?4096:(reg==2)?8192:16384) + (cidx<<10);
    if(reg<2){
      int m = m0 + row;
      const f16* p1 = ((reg==0)?A1h:A1l) + ((size_t)m<<9) + (g<<3);
      sp[i] = p1;
      if(AMODE==1){ int gv = gidx[m];
        sp2[i] = ((reg==0)?A2h:A2l) + (((size_t)gv<<21) + ((size_t)m<<9)) + (g<<3); }
      else if(AMODE==2){ int gv = gidx[m];
        sp2[i] = ((reg==0)?A2h:A2l) + ((size_t)gv<<7) + (g<<3); }
      else sp2[i] = p1;
    } else {
      int n = n0 + row;
      sp[i] = ((reg==2)?Bh:Bl) + (size_t)n*K + (g<<3);
      sp2[i] = sp[i];
    }
  }

  const int q = l>>4, r = l&15;
  int aoff[4], boff[2];
  #pragma unroll
  for(int i=0;i<4;i++) aoff[i] = slotb(16*i + r, q);
  #pragma unroll
  for(int j=0;j<2;j++) boff[j] = 8192 + slotb(w*32 + 16*j + r, q);

  f32x4 acc1[4][2] = {}, acc2[4][2] = {};

  // prologue: stage buf0 (k0 = 0)
  #pragma unroll
  for(int i=0;i<6;i++) gload16(sp[i], smem + loff[i]);
  __syncthreads();

  int buf = 0;
  for(int kt=0; kt<NK; ++kt){
    if(kt+1 < NK){
      int nb = buf^1;
      #pragma unroll
      for(int i=0;i<6;i++){
        int c = 6*w+i;
        if(AMODE!=0 && c<8 && (kt+1)==SW) sp[i] = sp2[i];
        else                              sp[i] += 32;
        gload16(sp[i], smem + nb*24576 + loff[i]);
      }
    }
    const char* Lb = smem + buf*24576;
    f16x8 ah[4], al[4], bh[2], bl[2];
    #pragma unroll
    for(int i=0;i<4;i++){
      ah[i] = *(const f16x8*)(Lb + aoff[i]);
      al[i] = *(const f16x8*)(Lb + 4096 + aoff[i]);
    }
    #pragma unroll
    for(int j=0;j<2;j++){
      bh[j] = *(const f16x8*)(Lb + boff[j]);
      bl[j] = *(const f16x8*)(Lb + 8192 + boff[j]);
    }
    #pragma unroll
    for(int i=0;i<4;i++)
      #pragma unroll
      for(int j=0;j<2;j++){
        acc1[i][j] = __builtin_amdgcn_mfma_f32_16x16x32_f16(ah[i], bh[j], acc1[i][j], 0,0,0);
        acc2[i][j] = __builtin_amdgcn_mfma_f32_16x16x32_f16(ah[i], bl[j], acc2[i][j], 0,0,0);
        acc2[i][j] = __builtin_amdgcn_mfma_f32_16x16x32_f16(al[i], bh[j], acc2[i][j], 0,0,0);
      }
    __syncthreads();
    buf ^= 1;
  }

  #pragma unroll
  for(int i=0;i<4;i++)
    #pragma unroll
    for(int j=0;j<2;j++)
      #pragma unroll
      for(int rr=0;rr<4;rr++){
        int rowm = m0 + 16*i + q*4 + rr;
        int coln = n0 + w*32 + 16*j + r;
        size_t o = ((size_t)rowm<<9) + coln;
        float v = acc1[i][j][rr] + acc2[i][j][rr]*(1.0f/2048.0f);
        v += bias[coln];
        if(EPI==2) v = fmaxf(v, 0.f);
        if(EPI==3) v += res[o];
        if(EPI==4) v += res[(((size_t)(rowm&255))<<9) + coln];
        if(EPI==1 || EPI==3 || EPI==4) Cf[o] = v;
        if(EPI==0 || EPI==2 || EPI==4){
          f16 h = (f16)v;
          f16 lo2 = (f16)((v - (float)h)*2048.0f);
          Ch[o] = h; Cl[o] = lo2;
          if(EPI==4){ C2h[o] = h; C2l[o] = lo2; }
        }
      }
}

// --- fp32 -> (hi, lo*2048) split -------------------------------------------
__global__ void split_k(const float* __restrict__ src, f16* __restrict__ hi,
                        f16* __restrict__ lo, int n){
  for(int i = blockIdx.x*256 + threadIdx.x; i < n; i += gridDim.x*256){
    float v = src[i];
    f16 h = (f16)v;
    hi[i] = h;
    lo[i] = (f16)((v - (float)h)*2048.0f);
  }
}

// --- wcomb[n*512+c][l] = sum_d cb[n][c][d] * sym_w[n][d][l]  (fp32, small) --
__global__ __launch_bounds__(256)
void wcomb_k(const float* __restrict__ A, const float* __restrict__ Wall,
             float* __restrict__ C)
{
  constexpr int T=256;
  __shared__ float As[32][68];
  __shared__ float Ws[32][132];
  const int tid = threadIdx.x;
  const int m0 = blockIdx.x*64, n0 = blockIdx.y*128;
  const float* W = Wall + (size_t)(m0>>9)*DS*DL;   // node-batched B
  const int ty = tid>>4, tx = tid&15;
  float4 pa[2], pw[4];
  auto loadA = [&](int k0){
    #pragma unroll
    for(int it=0; it<2; ++it){
      int v = tid + T*it; int rr = v>>3, c4 = v&7;
      pa[it] = *(const float4*)(A + (size_t)(m0+rr)*DS + k0 + (c4<<2));
    }
  };
  auto loadW = [&](int k0){
    #pragma unroll
    for(int it=0; it<4; ++it){
      int v = tid + T*it; int rr = v>>5, c4 = v&31;
      pw[it] = *(const float4*)(W + (size_t)(k0+rr)*DL + n0 + (c4<<2));
    }
  };
  float acc[4][8];
  #pragma unroll
  for(int i=0;i<4;i++)
    #pragma unroll
    for(int j=0;j<8;j++) acc[i][j]=0.f;
  loadA(0); loadW(0);
  for(int k0=0; k0<DS; k0+=32){
    __syncthreads();
    #pragma unroll
    for(int it=0; it<2; ++it){
      int v = tid + T*it; int rr=v>>3, c4=v&7;
      As[(c4<<2)+0][rr]=pa[it].x; As[(c4<<2)+1][rr]=pa[it].y;
      As[(c4<<2)+2][rr]=pa[it].z; As[(c4<<2)+3][rr]=pa[it].w;
    }
    #pragma unroll
    for(int it=0; it<4; ++it){
      int v = tid + T*it; int rr=v>>5, c4=v&31;
      *(float4*)&Ws[rr][c4<<2] = pw[it];
    }
    __syncthreads();
    if(k0+32 < DS){ loadA(k0+32); loadW(k0+32); }
    #pragma unroll
    for(int kk=0; kk<32; kk++){
      float4 a4 = *(const float4*)&As[kk][ty<<2];
      float4 b0 = *(const float4*)&Ws[kk][tx<<2];
      float4 b1 = *(const float4*)&Ws[kk][64+(tx<<2)];
      float a[4]={a4.x,a4.y,a4.z,a4.w};
      float b[8]={b0.x,b0.y,b0.z,b0.w,b1.x,b1.y,b1.z,b1.w};
      #pragma unroll
      for(int i=0;i<4;i++)
        #pragma unroll
        for(int j=0;j<8;j++) acc[i][j] = fmaf(a[i], b[j], acc[i][j]);
    }
  }
  #pragma unroll
  for(int i=0;i<4;i++){
    int m = m0 + (ty<<2) + i;
    #pragma unroll
    for(int j=0;j<8;j++){
      int n = n0 + ((j<4)? (tx<<2)+j : 64+(tx<<2)+(j-4));
      C[((size_t)m<<9)+n] = acc[i][j];
    }
  }
}

// --- init: active=1, msg={1,0..}, cons=0, relc slot0 = qry_b ---------------
__global__ void init_k(int* __restrict__ msg, int* __restrict__ act,
                       float* __restrict__ relc, const float* __restrict__ qb,
                       int* __restrict__ cons){
  int i = blockIdx.x*256 + threadIdx.x;
  if(i < TOK){
    act[i] = 1;
    #pragma unroll
    for(int nn=0;nn<4;nn++) relc[nn*TOK + i] = qb[nn];
  }
  if(i < 32){ msg[i] = (i==0) ? 1 : 0; cons[i] = 0; }
}

// --- combined quantizer bias: b2 = sym_b.cb - 0.5|cb|^2 --------------------
__global__ void bias2_k(const float* __restrict__ cb, const float* __restrict__ sb,
                        float* __restrict__ b2){
  int row = blockIdx.x*4 + (threadIdx.x>>6);
  int lane = threadIdx.x&63;
  const float* cv = cb + ((size_t)row<<7);
  const float* sbn = sb + ((row>>9)<<7);
  float c0=cv[lane], c1=cv[lane+64];
  float nrm = c0*c0 + c1*c1;
  float dt  = c0*sbn[lane] + c1*sbn[lane+64];
  nrm = wsum(nrm); dt = wsum(dt);
  if(lane==0) b2[row] = dt - 0.5f*nrm;
}

// --- per-token bus argmax (msg is the live snapshot during an op) ----------
__global__ void relmax_k(const float* __restrict__ relc, const int* __restrict__ msg,
                         int pt, int node, int* __restrict__ top, int* __restrict__ cons){
  int tok = blockIdx.x*256 + threadIdx.x;
  float best = -1e9f; int bs = 0;
  for(int s=0;s<pt;s++){
    float v = msg[s] ? relc[(size_t)((s<<2)+node)*TOK + tok] : -1e9f;
    if(v > best){ best = v; bs = s; }
  }
  top[tok] = bs;
  cons[bs] = 1;
}

// --- per-row argmax over 512 code scores (== argmin d2) --------------------
__global__ void codemax_k(const float* __restrict__ sc, int* __restrict__ idx){
  int m = blockIdx.x*4 + (threadIdx.x>>6);
  int lane = threadIdx.x&63;
  const float* row = sc + ((size_t)m<<9);
  float best = -INFINITY; int bi = 0;
  #pragma unroll
  for(int rr=0;rr<8;rr++){
    int c = lane + (rr<<6);
    float v = row[c];
    if(v > best){ best=v; bi=c; }
  }
  #pragma unroll
  for(int o=32;o>0;o>>=1){
    float ov = __shfl_xor(best,o);
    int   oi = __shfl_xor(bi,o);
    if(ov > best || (ov==best && oi<bi)){ best=ov; bi=oi; }
  }
  if(lane==0) idx[m]=bi;
}

// --- halting / update / append / rel-cache / mask-fold ---------------------
__global__ void mupdate_k(const float* __restrict__ no_, float* __restrict__ out,
                          f16* __restrict__ outh, f16* __restrict__ outl,
                          f16* __restrict__ slabh, f16* __restrict__ slabl,
                          float* __restrict__ relc, const int* __restrict__ idx,
                          const float* __restrict__ cbn, const float* __restrict__ qw,
                          const float* __restrict__ qb, int* __restrict__ act,
                          int* __restrict__ cons, int* __restrict__ msg,
                          int t, int ptr, int pe){
  int m = blockIdx.x*4 + (threadIdx.x>>6);
  int lane = threadIdx.x&63;
  const float* nrow = no_ + ((size_t)m<<9);
  float* orow = out + ((size_t)m<<9);
  float nv[8]; float s=0.f;
  #pragma unroll
  for(int rr=0;rr<8;rr++){
    int c = lane + (rr<<6);
    nv[rr]=nrow[c];
    float d = nv[rr]-orow[c]; s += d*d;
  }
  s = wsum(s);
  float delta = sqrtf(s);
  int a = act[m];
  int halt = (delta < 1e-3f) && a;
  int assigned = (t>0) ? a : 1;
  int upd = assigned && !halt;
  if(lane==0) act[m] = a && !halt;
  if(upd){
    #pragma unroll
    for(int rr=0;rr<8;rr++){
      int c = lane + (rr<<6);
      float v = nv[rr];
      orow[c] = v;
      f16 h = (f16)v;
      outh[((size_t)m<<9)+c] = h;
      outl[((size_t)m<<9)+c] = (f16)((v-(float)h)*2048.0f);
    }
  }
  if(ptr >= 0){
    size_t so = (((size_t)ptr)<<21) + ((size_t)m<<9);
    #pragma unroll
    for(int rr=0;rr<8;rr++){
      int c = lane + (rr<<6);
      float v = nv[rr];
      f16 h = (f16)v;
      slabh[so+c] = h;
      slabl[so+c] = (f16)((v-(float)h)*2048.0f);
    }
    const float* qv = cbn + ((size_t)idx[m]<<7);
    float q0=qv[lane], q1=qv[lane+64];
    #pragma unroll
    for(int nn=0;nn<4;nn++){
      float pr = q0*qw[(nn<<7)+lane] + q1*qw[(nn<<7)+64+lane];
      pr = wsum(pr);
      if(lane==0) relc[(size_t)((ptr<<2)+nn)*TOK + m] = pr + qb[nn];
    }
  }
  if(pe >= 0 && blockIdx.x==0 && threadIdx.x < 32){
    int s2 = threadIdx.x;
    msg[s2] = (s2 < pe) && !cons[s2];
    cons[s2] = 0;
  }
}

// ===========================================================================
// Legacy fp32 path (round-1, validated) — used only if ws is too small
// ===========================================================================
template<int AMODE,int WT,int EPI>
__global__ __launch_bounds__(256)
void gemm_k(const float* __restrict__ A, int lda,
            const float* __restrict__ W, int ldw,
            const float* __restrict__ bias,
            const float* __restrict__ res,
            const float* __restrict__ extra,
            const float* __restrict__ Ab,
            const int* __restrict__ rowsel,
            float* __restrict__ C, float* __restrict__ C2,
            int K, int K0)
{
  constexpr int BM=64, BN=128, BK=32, T=256;
  constexpr int AF4 = BM*BK/4/T;
  constexpr int WF4 = BN*BK/4/T;
  __shared__ float As[BK][BM+4];
  __shared__ float Ws[BK][BN+4];
  const int tid = threadIdx.x;
  const int m0 = blockIdx.x*BM, n0 = blockIdx.y*BN;
  const int ty = tid>>4, tx = tid&15;
  float4 pa[AF4], pw[WF4];
  auto loadA = [&](int k0){
    #pragma unroll
    for(int it=0; it<AF4; ++it){
      int v = tid + T*it;
      int rr = v>>3, c4 = v&7;
      int gr = m0 + rr, gc = k0 + (c4<<2);
      const float* src;
      if(AMODE==0)        src = A + (size_t)gr*lda + gc;
      else if(gc < K0)    src = A + (size_t)gr*lda + gc;
      else if(AMODE==1)   src = Ab + ((size_t)rowsel[gr]<<21) + ((size_t)gr<<9) + (gc-K0);
      else                src = Ab + ((size_t)rowsel[gr]<<7) + (gc-K0);
      pa[it] = *(const float4*)src;
    }
  };
  auto loadW = [&](int k0){
    #pragma unroll
    for(int it=0; it<WF4; ++it){
      int v = tid + T*it;
      if(WT==1){
        int rr = v>>3, c4 = v&7;
        pw[it] = *(const float4*)(W + (size_t)(n0+rr)*ldw + k0 + (c4<<2));
      } else {
        int rr = v>>5, c4 = v&31;
        pw[it] = *(const float4*)(W + (size_t)(k0+rr)*ldw + n0 + (c4<<2));
      }
    }
  };
  float acc[4][8];
  #pragma unroll
  for(int i=0;i<4;i++)
    #pragma unroll
    for(int j=0;j<8;j++) acc[i][j]=0.f;
  loadA(0); loadW(0);
  for(int k0=0; k0<K; k0+=BK){
    __syncthreads();
    #pragma unroll
    for(int it=0; it<AF4; ++it){
      int v = tid + T*it; int rr=v>>3, c4=v&7;
      As[(c4<<2)+0][rr]=pa[it].x; As[(c4<<2)+1][rr]=pa[it].y;
      As[(c4<<2)+2][rr]=pa[it].z; As[(c4<<2)+3][rr]=pa[it].w;
    }
    #pragma unroll
    for(int it=0; it<WF4; ++it){
      int v = tid + T*it;
      if(WT==1){
        int rr=v>>3, c4=v&7;
        Ws[(c4<<2)+0][rr]=pw[it].x; Ws[(c4<<2)+1][rr]=pw[it].y;
        Ws[(c4<<2)+2][rr]=pw[it].z; Ws[(c4<<2)+3][rr]=pw[it].w;
      } else {
        int rr=v>>5, c4=v&31;
        *(float4*)&Ws[rr][c4<<2] = pw[it];
      }
    }
    __syncthreads();
    if(k0+BK < K){ loadA(k0+BK); loadW(k0+BK); }
    #pragma unroll
    for(int kk=0; kk<BK; kk++){
      float4 a4 = *(const float4*)&As[kk][ty<<2];
      float4 b0 = *(const float4*)&Ws[kk][tx<<2];
      float4 b1 = *(const float4*)&Ws[kk][64+(tx<<2)];
      float a[4]={a4.x,a4.y,a4.z,a4.w};
      float b[8]={b0.x,b0.y,b0.z,b0.w,b1.x,b1.y,b1.z,b1.w};
      #pragma unroll
      for(int i=0;i<4;i++)
        #pragma unroll
        for(int j=0;j<8;j++)
          acc[i][j] = fmaf(a[i], b[j], acc[i][j]);
    }
  }
  #pragma unroll
  for(int i=0;i<4;i++){
    int m = m0 + (ty<<2) + i;
    float v0[4], v1[4];
    #pragma unroll
    for(int j=0;j<8;j++){
      int n = n0 + ((j<4)? (tx<<2)+j : 64+(tx<<2)+(j-4));
      float v = acc[i][j];
      if(bias) v += bias[n];
      if(EPI==1) v = fmaxf(v,0.f);
      if(EPI==2) v += res[((size_t)m<<9)+n];
      if(EPI==4) v += extra[((size_t)(m&255)<<9)+n];
      if(j<4) v0[j]=v; else v1[j-4]=v;
    }
    *(float4*)&C[((size_t)m<<9) + n0 + (tx<<2)]      = make_float4(v0[0],v0[1],v0[2],v0[3]);
    *(float4*)&C[((size_t)m<<9) + n0 + 64 + (tx<<2)] = make_float4(v1[0],v1[1],v1[2],v1[3]);
    if(EPI==4){
      *(float4*)&C2[((size_t)m<<9) + n0 + (tx<<2)]      = make_float4(v0[0],v0[1],v0[2],v0[3]);
      *(float4*)&C2[((size_t)m<<9) + n0 + 64 + (tx<<2)] = make_float4(v1[0],v1[1],v1[2],v1[3]);
    }
  }
}

__global__ void snap_k(const int* __restrict__ msg, int* __restrict__ snap,
                       int* __restrict__ cons, int pt){
  int i = threadIdx.x;
  if(i<32){ snap[i] = (msg[i] && (i<pt)) ? 1:0; cons[i]=0; }
}
__global__ void mask_k(int* __restrict__ msg, const int* __restrict__ cons, int pe){
  int i = threadIdx.x;
  if(i<32) msg[i] = ((i<pe) && !cons[i]) ? 1:0;
}
__global__ void relmax_leg(const float* __restrict__ relc, const int* __restrict__ snap,
                           int pt, int node, int* __restrict__ top, int* __restrict__ cons){
  int tok = blockIdx.x*256 + threadIdx.x;
  float best = -1e9f; int bs = 0;
  for(int s=0;s<pt;s++){
    float v = snap[s] ? relc[(size_t)((s<<2)+node)*TOK + tok] : -1e9f;
    if(v > best){ best = v; bs = s; }
  }
  top[tok] = bs;
  cons[bs] = 1;
}
__global__ void update_leg(const float* __restrict__ no_, float* __restrict__ out,
                           float* __restrict__ slab, float* __restrict__ relc,
                           const int* __restrict__ idx, const float* __restrict__ cbn,
                           const float* __restrict__ qw, const float* __restrict__ qb,
                           int* __restrict__ act, int t, int ptr){
  int m = blockIdx.x*4 + (threadIdx.x>>6);
  int lane = threadIdx.x&63;
  const float* nrow = no_ + ((size_t)m<<9);
  float* orow = out + ((size_t)m<<9);
  float nv[8]; float s=0.f;
  #pragma unroll
  for(int rr=0;rr<8;rr++){
    int c = lane + (rr<<6);
    nv[rr]=nrow[c];
    float d = nv[rr]-orow[c]; s += d*d;
  }
  s = wsum(s);
  float delta = sqrtf(s);
  int a = act[m];
  int halt = (delta < 1e-3f) && a;
  int assigned = (t>0) ? a : 1;
  int upd = assigned && !halt;
  if(lane==0) act[m] = a && !halt;
  if(upd){
    #pragma unroll
    for(int rr=0;rr<8;rr++) orow[lane+(rr<<6)] = nv[rr];
  }
  if(ptr >= 0){
    float* srow = slab + (((size_t)ptr)<<21) + ((size_t)m<<9);
    #pragma unroll
    for(int rr=0;rr<8;rr++) srow[lane+(rr<<6)] = nv[rr];
    const float* qv = cbn + ((size_t)idx[m]<<7);
    float q0=qv[lane], q1=qv[lane+64];
    #pragma unroll
    for(int nn=0;nn<4;nn++){
      float pr = q0*qw[(nn<<7)+lane] + q1*qw[(nn<<7)+64+lane];
      pr = wsum(pr);
      if(lane==0) relc[(size_t)((ptr<<2)+nn)*TOK + m] = pr + qb[nn];
    }
  }
}

} // namespace

extern "C" void kernel_launch(void* const* d_in, const int* in_sizes, int n_in,
                              void* d_out, int out_size, void* d_ws, size_t ws_size,
                              hipStream_t stream)
{
  (void)in_sizes; (void)n_in; (void)out_size;
  const float* x   = (const float*)d_in[0];
  const float* ipw = (const float*)d_in[1];
  const float* ipb = (const float*)d_in[2];
  const float* tp  = (const float*)d_in[3];
  const float* sw  = (const float*)d_in[4];
  const float* sb  = (const float*)d_in[5];
  const float* qw  = (const float*)d_in[6];
  const float* qb  = (const float*)d_in[7];
  const float* rw  = (const float*)d_in[8];
  const float* rb  = (const float*)d_in[9];
  const float* c1w = (const float*)d_in[10];
  const float* c1b = (const float*)d_in[11];
  const float* c2w = (const float*)d_in[12];
  const float* c2b = (const float*)d_in[13];
  const float* cb  = (const float*)d_in[14];
  float* out = (float*)d_out;

  const size_t NEED_NEW = 168000000ull;
  if(ws_size >= NEED_NEW){
    // ---------------- fp16x2-split MFMA path ----------------
    char* p = (char*)d_ws;
    auto alloc = [&](size_t b)->char*{ char* r=p; p += (b+255)&~(size_t)255; return r; };
    f16* slabh = (f16*)alloc((size_t)NSLOT*TOK*DL*2);
    f16* slabl = (f16*)alloc((size_t)NSLOT*TOK*DL*2);
    f16* outh  = (f16*)alloc((size_t)TOK*DL*2);
    f16* outl  = (f16*)alloc((size_t)TOK*DL*2);
    f16* zh    = (f16*)alloc((size_t)TOK*DL*2);
    f16* zl    = (f16*)alloc((size_t)TOK*DL*2);
    f16* hh    = (f16*)alloc((size_t)TOK*DL*2);
    f16* hl    = (f16*)alloc((size_t)TOK*DL*2);
    float* sn  = (float*)alloc((size_t)TOK*DL*4);      // score / nodeo / wcomb32
    f16* rwh   = (f16*)alloc((size_t)4*DL*1024*2);
    f16* rwl   = (f16*)alloc((size_t)4*DL*1024*2);
    f16* c1h   = (f16*)alloc((size_t)4*DL*640*2);
    f16* c1l   = (f16*)alloc((size_t)4*DL*640*2);
    f16* c2h   = (f16*)alloc((size_t)4*DL*DL*2);
    f16* c2l   = (f16*)alloc((size_t)4*DL*DL*2);
    f16* wch   = (f16*)alloc((size_t)4*NC*DL*2);
    f16* wcl   = (f16*)alloc((size_t)4*NC*DL*2);
    f16* iph   = (f16*)alloc((size_t)DL*DL*2);
    f16* ipl   = (f16*)alloc((size_t)DL*DL*2);
    f16* cbh   = (f16*)alloc((size_t)4*NC*DS*2);
    f16* cbl   = (f16*)alloc((size_t)4*NC*DS*2);
    float* b2  = (float*)alloc(4*NC*4);
    float* relc= (float*)alloc((size_t)NSLOT*4*TOK*4);
    int* top   = (int*)alloc(TOK*4);
    int* idxb  = (int*)alloc(TOK*4);
    int* act   = (int*)alloc(TOK*4);
    int* msg   = (int*)alloc(256);
    int* cons  = (int*)alloc(256);

    dim3 G(64,4), B(256);

    init_k<<<16,256,0,stream>>>(msg, act, relc, qb, cons);
    bias2_k<<<512,256,0,stream>>>(cb, sb, b2);
    wcomb_k<<<dim3(32,4),B,0,stream>>>(cb, sw, sn);
    split_k<<<2048,256,0,stream>>>(x,   hh,  hl,  TOK*DL);
    split_k<<<512 ,256,0,stream>>>(ipw, iph, ipl, DL*DL);
    split_k<<<2048,256,0,stream>>>(rw,  rwh, rwl, 4*DL*1024);
    split_k<<<2048,256,0,stream>>>(c1w, c1h, c1l, 4*DL*640);
    split_k<<<1024,256,0,stream>>>(c2w, c2h, c2l, 4*DL*DL);
    split_k<<<512 ,256,0,stream>>>(cb,  cbh, cbl, 4*NC*DS);
    split_k<<<1024,256,0,stream>>>(sn,  wch, wcl, 4*NC*DL);

    // input projection + prompts -> out(fp32)+planes, slab slot0 planes
    mgemm<0,4><<<G,B,0,stream>>>(hh,hl, nullptr,nullptr, nullptr, iph,ipl,
        ipb, tp, out, outh,outl, slabh,slabl, DL, DL);

    int ptr = 1;
    for(int t=0;t<4;t++){
      int pt = 1 + 4*t;
      for(int n=0;n<4;n++){
        relmax_k<<<16,256,0,stream>>>(relc, msg, pt, n, top, cons);
        mgemm<1,0><<<G,B,0,stream>>>(outh,outl, slabh,slabl, top,
            rwh+(size_t)n*DL*1024, rwl+(size_t)n*DL*1024, rb+(size_t)n*DL,
            nullptr, nullptr, zh,zl, nullptr,nullptr, 1024, 512);
        mgemm<0,1><<<G,B,0,stream>>>(zh,zl, nullptr,nullptr, nullptr,
            wch+(size_t)n*NC*DL, wcl+(size_t)n*NC*DL, b2+(size_t)n*NC,
            nullptr, sn, nullptr,nullptr, nullptr,nullptr, 512, 512);
        codemax_k<<<1024,256,0,stream>>>(sn, idxb);
        mgemm<2,2><<<G,B,0,stream>>>(zh,zl, cbh+(size_t)n*NC*DS, cbl+(size_t)n*NC*DS, idxb,
            c1h+(size_t)n*DL*640, c1l+(size_t)n*DL*640, c1b+(size_t)n*DL,
            nullptr, nullptr, hh,hl, nullptr,nullptr, 640, 512);
        mgemm<0,3><<<G,B,0,stream>>>(hh,hl, nullptr,nullptr, nullptr,
            c2h+(size_t)n*DL*DL, c2l+(size_t)n*DL*DL, c2b+(size_t)n*DL,
            out, sn, nullptr,nullptr, nullptr,nullptr, 512, 512);
        mupdate_k<<<1024,256,0,stream>>>(sn, out, outh,outl, slabh,slabl, relc, idxb,
            cb+(size_t)n*NC*DS, qw, qb, act, cons, msg, t,
            (t<3)? ptr : -1, (n==3 && t<3)? (1+4*(t+1)) : -1);
        ptr++;
      }
    }
  } else {
    // ---------------- legacy fp32 path (round-1, validated) ----------------
    float* ws = (float*)d_ws;
    float* slab  = ws;
    float* zread = slab  + (size_t)NSLOT*TOK*DL;
    float* hid   = zread + (size_t)TOK*DL;
    float* nodeo = hid   + (size_t)TOK*DL;
    float* score = nodeo + (size_t)TOK*DL;
    float* wcomb = score + (size_t)TOK*NC;
    float* b2    = wcomb + (size_t)4*NC*DL;
    float* relc  = b2    + (size_t)4*NC;
    int* top  = (int*)(relc + (size_t)NSLOT*4*TOK);
    int* idxb = top + TOK;
    int* act  = idxb + TOK;
    int* msg  = act + TOK;
    int* cons = msg + 32;
    int* snap = cons + 32;

    dim3 G(TOK/64, 4), B(256);
    init_k<<<16,256,0,stream>>>(msg, act, relc, qb, cons);
    bias2_k<<<512,256,0,stream>>>(cb, sb, b2);
    for(int n=0;n<4;n++)
      gemm_k<0,0,0><<<dim3(8,4),B,0,stream>>>(cb + (size_t)n*NC*DS, DS,
          sw + (size_t)n*DS*DL, DL, nullptr, nullptr, nullptr, nullptr, nullptr,
          wcomb + (size_t)n*NC*DL, nullptr, DS, DL);
    gemm_k<0,1,4><<<G,B,0,stream>>>(x, DL, ipw, DL, ipb, nullptr, tp, nullptr, nullptr,
          out, slab, DL, DL);
    int ptr = 1;
    for(int t=0;t<4;t++){
      int pt = ptr;
      snap_k<<<1,64,0,stream>>>(msg, snap, cons, pt);
      for(int n=0;n<4;n++){
        relmax_leg<<<16,256,0,stream>>>(relc, snap, pt, n, top, cons);
        gemm_k<1,1,0><<<G,B,0,stream>>>(out, DL, rw + (size_t)n*DL*2*DL, 2*DL,
            rb + (size_t)n*DL, nullptr, nullptr, slab, top, zread, nullptr, 2*DL, DL);
        gemm_k<0,1,0><<<G,B,0,stream>>>(zread, DL, wcomb + (size_t)n*NC*DL, DL,
            b2 + n*NC, nullptr, nullptr, nullptr, nullptr, score, nullptr, DL, DL);
        codemax_k<<<1024,256,0,stream>>>(score, idxb);
        gemm_k<2,1,1><<<G,B,0,stream>>>(zread, DL, c1w + (size_t)n*DL*(DL+DS), DL+DS,
            c1b + (size_t)n*DL, nullptr, nullptr, cb + (size_t)n*NC*DS, idxb, hid, nullptr, DL+DS, DL);
        gemm_k<0,1,2><<<G,B,0,stream>>>(hid, DL, c2w + (size_t)n*DL*DL, DL,
            c2b + (size_t)n*DL, out, nullptr, nullptr, nullptr, nodeo, nullptr, DL, DL);
        update_leg<<<1024,256,0,stream>>>(nodeo, out, slab, relc, idxb,
            cb + (size_t)n*NC*DS, qw, qb, act, t, (t<3)? ptr : -1);
        ptr++;
      }
      if(t<3) mask_k<<<1,64,0,stream>>>(msg, cons, ptr);
    }
  }
}

// Round 4
// 1320.800 us; speedup vs baseline: 2.7890x; 1.1294x over previous
//
#include <hip/hip_runtime.h>
#include <math.h>

namespace {

typedef _Float16 f16;
typedef __attribute__((ext_vector_type(8))) _Float16 f16x8;
typedef __attribute__((ext_vector_type(4))) float f32x4;

constexpr int TOK = 4096;
constexpr int DL  = 512;
constexpr int DS  = 128;
constexpr int NC  = 512;
constexpr int NSLOT = 13;

__device__ __forceinline__ float wsum(float v){
  #pragma unroll
  for(int o=32;o>0;o>>=1) v += __shfl_xor(v,o);
  return v;
}

__device__ __forceinline__ void gload16(const void* g, void* l){
  __builtin_amdgcn_global_load_lds(
      (const __attribute__((address_space(1))) unsigned int*)g,
      (__attribute__((address_space(3))) unsigned int*)l, 16, 0, 0);
}

// byte offset of the 16B slot holding (row, 16B-granule g) — bank-spread bijection
__device__ __forceinline__ int slotb(int row, int g){
  return (((row ^ ((row>>2)&1))<<2) | (g ^ (row&3))) << 4;
}

// ===========================================================================
// fp16x2-split MFMA GEMM, BM=64 BN=64 BK=32, 4 waves (each a 32x32 tile).
// C[m, n0..n0+64) = A[m,:K] * W[n,:K]^T (+ epilogue). Grid (64, 8).
// 2 blocks/CU (32KB LDS, launch_bounds(256,2)) so staging drains overlap MFMA.
// A part1: hi/lo planes, row stride 512. Part2 (cols >= K0):
//   AMODE 0: none; 1: slab[gidx[m]] (slot<<21 + m<<9); 2: cb row gidx[m] (128)
// B: hi/lo planes [512][K].
// EPI: 0 planes (zread) ; 1 fp32 (score) ; 2 relu planes (hid)
//      3 fp32 + fp32-res (nodeo) ; 4 fp32 + prompt + planes + slab0 planes
// ===========================================================================
template<int AMODE,int EPI>
__global__ __launch_bounds__(256,2) void mgemm(
    const f16* __restrict__ A1h, const f16* __restrict__ A1l,
    const f16* __restrict__ A2h, const f16* __restrict__ A2l,
    const int* __restrict__ gidx,
    const f16* __restrict__ Bh, const f16* __restrict__ Bl,
    const float* __restrict__ bias, const float* __restrict__ res,
    float* __restrict__ Cf, f16* __restrict__ Ch, f16* __restrict__ Cl,
    f16* __restrict__ C2h, f16* __restrict__ C2l,
    int K, int K0)
{
  constexpr int SMB = 16384;  // Ah 4K | Al 4K | Bh 4K | Bl 4K
  __shared__ __align__(16) char smem[2*SMB];
  const int tid = threadIdx.x, w = tid>>6, l = tid&63;
  const int m0 = blockIdx.x*64, n0 = blockIdx.y*64;
  const int NK = K>>5, SW = K0>>5;

  // staging: 16 chunks of 1KB per K-step; wave w owns chunks [4w, 4w+4)
  const f16* sp[4]; const f16* sp2[4]; int loff[4];
  #pragma unroll
  for(int i=0;i<4;i++){
    int c = 4*w+i;
    int isA = (c<8);
    int plane = isA ? (c>>2) : ((c-8)>>2);
    int cidx  = isA ? (c&3)  : ((c-8)&3);
    loff[i] = (isA?0:8192) + plane*4096 + cidx*1024;
    int s = (cidx<<6) + l;                      // linear LDS slot this lane fills
    int rp = s>>2, row = rp ^ ((rp>>2)&1), g = (s&3) ^ (row&3);  // inverse slotb
    int g8 = g<<3;
    if(isA){
      int m = m0 + row;
      const f16* p1 = (plane? A1l : A1h) + ((size_t)m<<9) + g8;
      sp[i] = p1;
      if(AMODE==1)      sp2[i] = (plane? A2l : A2h) + ((size_t)gidx[m]<<21) + ((size_t)m<<9) + g8;
      else if(AMODE==2) sp2[i] = (plane? A2l : A2h) + ((size_t)gidx[m]<<7) + g8;
      else              sp2[i] = p1;
    } else {
      sp[i] = (plane? Bl : Bh) + (size_t)(n0+row)*K + g8;
      sp2[i] = sp[i];
    }
  }

  const int wr = w>>1, wc = w&1, q = l>>4, r = l&15;
  int aoff[2], boff[2];
  #pragma unroll
  for(int i=0;i<2;i++) aoff[i] = slotb(32*wr + 16*i + r, q);
  #pragma unroll
  for(int j=0;j<2;j++) boff[j] = 8192 + slotb(32*wc + 16*j + r, q);

  f32x4 acc1[2][2] = {}, acc2[2][2] = {};

  #pragma unroll
  for(int i=0;i<4;i++) gload16(sp[i], smem + loff[i]);
  __syncthreads();

  int buf = 0;
  for(int kt=0; kt<NK; ++kt){
    if(kt+1 < NK){
      int nb = buf^1;
      #pragma unroll
      for(int i=0;i<4;i++){
        if(AMODE!=0 && (4*w+i)<8 && (kt+1)==SW) sp[i] = sp2[i];
        else                                     sp[i] += 32;
        gload16(sp[i], smem + nb*SMB + loff[i]);
      }
    }
    const char* Lb = smem + buf*SMB;
    f16x8 ah[2], al[2], bh[2], bl[2];
    #pragma unroll
    for(int i=0;i<2;i++){
      ah[i] = *(const f16x8*)(Lb + aoff[i]);
      al[i] = *(const f16x8*)(Lb + 4096 + aoff[i]);
    }
    #pragma unroll
    for(int j=0;j<2;j++){
      bh[j] = *(const f16x8*)(Lb + boff[j]);
      bl[j] = *(const f16x8*)(Lb + 4096 + boff[j]);
    }
    #pragma unroll
    for(int i=0;i<2;i++)
      #pragma unroll
      for(int j=0;j<2;j++){
        acc1[i][j] = __builtin_amdgcn_mfma_f32_16x16x32_f16(ah[i], bh[j], acc1[i][j], 0,0,0);
        acc2[i][j] = __builtin_amdgcn_mfma_f32_16x16x32_f16(ah[i], bl[j], acc2[i][j], 0,0,0);
        acc2[i][j] = __builtin_amdgcn_mfma_f32_16x16x32_f16(al[i], bh[j], acc2[i][j], 0,0,0);
      }
    __syncthreads();
    buf ^= 1;
  }

  #pragma unroll
  for(int i=0;i<2;i++)
    #pragma unroll
    for(int j=0;j<2;j++)
      #pragma unroll
      for(int rr=0;rr<4;rr++){
        int rowm = m0 + 32*wr + 16*i + 4*q + rr;
        int coln = n0 + 32*wc + 16*j + r;
        size_t o = ((size_t)rowm<<9) + coln;
        float v = acc1[i][j][rr] + acc2[i][j][rr]*(1.0f/2048.0f) + bias[coln];
        if(EPI==2) v = fmaxf(v, 0.f);
        if(EPI==3) v += res[o];
        if(EPI==4) v += res[(((size_t)(rowm&255))<<9) + coln];
        if(EPI==1 || EPI==3 || EPI==4) Cf[o] = v;
        if(EPI==0 || EPI==2 || EPI==4){
          f16 h = (f16)v;
          Ch[o] = h; Cl[o] = (f16)((v-(float)h)*2048.0f);
        }
        if(EPI==4){
          f16 h = (f16)v;
          C2h[o] = h; C2l[o] = (f16)((v-(float)h)*2048.0f);
        }
      }
}

// --- fp32 -> (hi, lo*2048) split -------------------------------------------
__global__ void split_k(const float* __restrict__ src, f16* __restrict__ hi,
                        f16* __restrict__ lo, int n){
  for(int i = blockIdx.x*256 + threadIdx.x; i < n; i += gridDim.x*256){
    float v = src[i];
    f16 h = (f16)v;
    hi[i] = h;
    lo[i] = (f16)((v - (float)h)*2048.0f);
  }
}

// --- wcomb[n*512+c][l] = sum_d cb[n][c][d] * sym_w[n][d][l]  (fp32, small) --
__global__ __launch_bounds__(256)
void wcomb_k(const float* __restrict__ A, const float* __restrict__ Wall,
             float* __restrict__ C)
{
  constexpr int T=256;
  __shared__ float As[32][68];
  __shared__ float Ws[32][132];
  const int tid = threadIdx.x;
  const int m0 = blockIdx.x*64, n0 = blockIdx.y*128;
  const float* W = Wall + (size_t)(m0>>9)*DS*DL;
  const int ty = tid>>4, tx = tid&15;
  float4 pa[2], pw[4];
  auto loadA = [&](int k0){
    #pragma unroll
    for(int it=0; it<2; ++it){
      int v = tid + T*it; int rr = v>>3, c4 = v&7;
      pa[it] = *(const float4*)(A + (size_t)(m0+rr)*DS + k0 + (c4<<2));
    }
  };
  auto loadW = [&](int k0){
    #pragma unroll
    for(int it=0; it<4; ++it){
      int v = tid + T*it; int rr = v>>5, c4 = v&31;
      pw[it] = *(const float4*)(W + (size_t)(k0+rr)*DL + n0 + (c4<<2));
    }
  };
  float acc[4][8];
  #pragma unroll
  for(int i=0;i<4;i++)
    #pragma unroll
    for(int j=0;j<8;j++) acc[i][j]=0.f;
  loadA(0); loadW(0);
  for(int k0=0; k0<DS; k0+=32){
    __syncthreads();
    #pragma unroll
    for(int it=0; it<2; ++it){
      int v = tid + T*it; int rr=v>>3, c4=v&7;
      As[(c4<<2)+0][rr]=pa[it].x; As[(c4<<2)+1][rr]=pa[it].y;
      As[(c4<<2)+2][rr]=pa[it].z; As[(c4<<2)+3][rr]=pa[it].w;
    }
    #pragma unroll
    for(int it=0; it<4; ++it){
      int v = tid + T*it; int rr=v>>5, c4=v&31;
      *(float4*)&Ws[rr][c4<<2] = pw[it];
    }
    __syncthreads();
    if(k0+32 < DS){ loadA(k0+32); loadW(k0+32); }
    #pragma unroll
    for(int kk=0; kk<32; kk++){
      float4 a4 = *(const float4*)&As[kk][ty<<2];
      float4 b0 = *(const float4*)&Ws[kk][tx<<2];
      float4 b1 = *(const float4*)&Ws[kk][64+(tx<<2)];
      float a[4]={a4.x,a4.y,a4.z,a4.w};
      float b[8]={b0.x,b0.y,b0.z,b0.w,b1.x,b1.y,b1.z,b1.w};
      #pragma unroll
      for(int i=0;i<4;i++)
        #pragma unroll
        for(int j=0;j<8;j++) acc[i][j] = fmaf(a[i], b[j], acc[i][j]);
    }
  }
  #pragma unroll
  for(int i=0;i<4;i++){
    int m = m0 + (ty<<2) + i;
    #pragma unroll
    for(int j=0;j<8;j++){
      int n = n0 + ((j<4)? (tx<<2)+j : 64+(tx<<2)+(j-4));
      C[((size_t)m<<9)+n] = acc[i][j];
    }
  }
}

// --- init: active=1, msg={1,0..}, cons=0, relc slot0 = qry_b ---------------
__global__ void init_k(int* __restrict__ msg, int* __restrict__ act,
                       float* __restrict__ relc, const float* __restrict__ qb,
                       int* __restrict__ cons){
  int i = blockIdx.x*256 + threadIdx.x;
  if(i < TOK){
    act[i] = 1;
    #pragma unroll
    for(int nn=0;nn<4;nn++) relc[nn*TOK + i] = qb[nn];
  }
  if(i < 32){ msg[i] = (i==0) ? 1 : 0; cons[i] = 0; }
}

// --- combined quantizer bias: b2 = sym_b.cb - 0.5|cb|^2 --------------------
__global__ void bias2_k(const float* __restrict__ cb, const float* __restrict__ sb,
                        float* __restrict__ b2){
  int row = blockIdx.x*4 + (threadIdx.x>>6);
  int lane = threadIdx.x&63;
  const float* cv = cb + ((size_t)row<<7);
  const float* sbn = sb + ((row>>9)<<7);
  float c0=cv[lane], c1=cv[lane+64];
  float nrm = c0*c0 + c1*c1;
  float dt  = c0*sbn[lane] + c1*sbn[lane+64];
  nrm = wsum(nrm); dt = wsum(dt);
  if(lane==0) b2[row] = dt - 0.5f*nrm;
}

// --- per-token bus argmax (msg is the live snapshot during an op) ----------
__global__ void relmax_k(const float* __restrict__ relc, const int* __restrict__ msg,
                         int pt, int node, int* __restrict__ top, int* __restrict__ cons){
  int tok = blockIdx.x*256 + threadIdx.x;
  float best = -1e9f; int bs = 0;
  for(int s=0;s<pt;s++){
    float v = msg[s] ? relc[(size_t)((s<<2)+node)*TOK + tok] : -1e9f;
    if(v > best){ best = v; bs = s; }
  }
  top[tok] = bs;
  cons[bs] = 1;
}

// --- per-row argmax over 512 code scores (== argmin d2) --------------------
__global__ void codemax_k(const float* __restrict__ sc, int* __restrict__ idx){
  int m = blockIdx.x*4 + (threadIdx.x>>6);
  int lane = threadIdx.x&63;
  const float* row = sc + ((size_t)m<<9);
  float best = -INFINITY; int bi = 0;
  #pragma unroll
  for(int rr=0;rr<8;rr++){
    int c = lane + (rr<<6);
    float v = row[c];
    if(v > best){ best=v; bi=c; }
  }
  #pragma unroll
  for(int o=32;o>0;o>>=1){
    float ov = __shfl_xor(best,o);
    int   oi = __shfl_xor(bi,o);
    if(ov > best || (ov==best && oi<bi)){ best=ov; bi=oi; }
  }
  if(lane==0) idx[m]=bi;
}

// --- halting / update / append / rel-cache / mask-fold ---------------------
__global__ void mupdate_k(const float* __restrict__ no_, float* __restrict__ out,
                          f16* __restrict__ outh, f16* __restrict__ outl,
                          f16* __restrict__ slabh, f16* __restrict__ slabl,
                          float* __restrict__ relc, const int* __restrict__ idx,
                          const float* __restrict__ cbn, const float* __restrict__ qw,
                          const float* __restrict__ qb, int* __restrict__ act,
                          int* __restrict__ cons, int* __restrict__ msg,
                          int t, int ptr, int pe){
  int m = blockIdx.x*4 + (threadIdx.x>>6);
  int lane = threadIdx.x&63;
  const float* nrow = no_ + ((size_t)m<<9);
  float* orow = out + ((size_t)m<<9);
  float nv[8]; float s=0.f;
  #pragma unroll
  for(int rr=0;rr<8;rr++){
    int c = lane + (rr<<6);
    nv[rr]=nrow[c];
    float d = nv[rr]-orow[c]; s += d*d;
  }
  s = wsum(s);
  float delta = sqrtf(s);
  int a = act[m];
  int halt = (delta < 1e-3f) && a;
  int assigned = (t>0) ? a : 1;
  int upd = assigned && !halt;
  if(lane==0) act[m] = a && !halt;
  if(upd){
    #pragma unroll
    for(int rr=0;rr<8;rr++){
      int c = lane + (rr<<6);
      float v = nv[rr];
      orow[c] = v;
      f16 h = (f16)v;
      outh[((size_t)m<<9)+c] = h;
      outl[((size_t)m<<9)+c] = (f16)((v-(float)h)*2048.0f);
    }
  }
  if(ptr >= 0){
    size_t so = (((size_t)ptr)<<21) + ((size_t)m<<9);
    #pragma unroll
    for(int rr=0;rr<8;rr++){
      int c = lane + (rr<<6);
      float v = nv[rr];
      f16 h = (f16)v;
      slabh[so+c] = h;
      slabl[so+c] = (f16)((v-(float)h)*2048.0f);
    }
    const float* qv = cbn + ((size_t)idx[m]<<7);
    float q0=qv[lane], q1=qv[lane+64];
    #pragma unroll
    for(int nn=0;nn<4;nn++){
      float pr = q0*qw[(nn<<7)+lane] + q1*qw[(nn<<7)+64+lane];
      pr = wsum(pr);
      if(lane==0) relc[(size_t)((ptr<<2)+nn)*TOK + m] = pr + qb[nn];
    }
  }
  if(pe >= 0 && blockIdx.x==0 && threadIdx.x < 32){
    int s2 = threadIdx.x;
    msg[s2] = (s2 < pe) && !cons[s2];
    cons[s2] = 0;
  }
}

} // namespace

extern "C" void kernel_launch(void* const* d_in, const int* in_sizes, int n_in,
                              void* d_out, int out_size, void* d_ws, size_t ws_size,
                              hipStream_t stream)
{
  (void)in_sizes; (void)n_in; (void)out_size; (void)ws_size;
  const float* x   = (const float*)d_in[0];
  const float* ipw = (const float*)d_in[1];
  const float* ipb = (const float*)d_in[2];
  const float* tp  = (const float*)d_in[3];
  const float* sw  = (const float*)d_in[4];
  const float* sb  = (const float*)d_in[5];
  const float* qw  = (const float*)d_in[6];
  const float* qb  = (const float*)d_in[7];
  const float* rw  = (const float*)d_in[8];
  const float* rb  = (const float*)d_in[9];
  const float* c1w = (const float*)d_in[10];
  const float* c1b = (const float*)d_in[11];
  const float* c2w = (const float*)d_in[12];
  const float* c2b = (const float*)d_in[13];
  const float* cb  = (const float*)d_in[14];
  float* out = (float*)d_out;

  char* p = (char*)d_ws;
  auto alloc = [&](size_t b)->char*{ char* r=p; p += (b+255)&~(size_t)255; return r; };
  f16* slabh = (f16*)alloc((size_t)NSLOT*TOK*DL*2);
  f16* slabl = (f16*)alloc((size_t)NSLOT*TOK*DL*2);
  f16* outh  = (f16*)alloc((size_t)TOK*DL*2);
  f16* outl  = (f16*)alloc((size_t)TOK*DL*2);
  f16* zh    = (f16*)alloc((size_t)TOK*DL*2);
  f16* zl    = (f16*)alloc((size_t)TOK*DL*2);
  f16* hh    = (f16*)alloc((size_t)TOK*DL*2);
  f16* hl    = (f16*)alloc((size_t)TOK*DL*2);
  float* sn  = (float*)alloc((size_t)TOK*DL*4);      // score/nodeo fp32 + wcomb staging
  f16* rwh   = (f16*)alloc((size_t)4*DL*1024*2);
  f16* rwl   = (f16*)alloc((size_t)4*DL*1024*2);
  f16* c1h   = (f16*)alloc((size_t)4*DL*640*2);
  f16* c1l   = (f16*)alloc((size_t)4*DL*640*2);
  f16* c2h   = (f16*)alloc((size_t)4*DL*DL*2);
  f16* c2l   = (f16*)alloc((size_t)4*DL*DL*2);
  f16* wch   = (f16*)alloc((size_t)4*NC*DL*2);
  f16* wcl   = (f16*)alloc((size_t)4*NC*DL*2);
  f16* iph   = (f16*)alloc((size_t)DL*DL*2);
  f16* ipl   = (f16*)alloc((size_t)DL*DL*2);
  f16* cbh   = (f16*)alloc((size_t)4*NC*DS*2);
  f16* cbl   = (f16*)alloc((size_t)4*NC*DS*2);
  float* b2  = (float*)alloc(4*NC*4);
  float* relc= (float*)alloc((size_t)NSLOT*4*TOK*4);
  int* top   = (int*)alloc(TOK*4);
  int* idxb  = (int*)alloc(TOK*4);
  int* act   = (int*)alloc(TOK*4);
  int* msg   = (int*)alloc(256);
  int* cons  = (int*)alloc(256);

  dim3 G(64,8), B(256);

  init_k<<<16,256,0,stream>>>(msg, act, relc, qb, cons);
  bias2_k<<<512,256,0,stream>>>(cb, sb, b2);
  wcomb_k<<<dim3(32,4),B,0,stream>>>(cb, sw, sn);
  split_k<<<2048,256,0,stream>>>(x,   hh,  hl,  TOK*DL);   // x planes staged in hh/hl
  split_k<<<512 ,256,0,stream>>>(ipw, iph, ipl, DL*DL);
  split_k<<<2048,256,0,stream>>>(rw,  rwh, rwl, 4*DL*1024);
  split_k<<<2048,256,0,stream>>>(c1w, c1h, c1l, 4*DL*640);
  split_k<<<1024,256,0,stream>>>(c2w, c2h, c2l, 4*DL*DL);
  split_k<<<512 ,256,0,stream>>>(cb,  cbh, cbl, 4*NC*DS);
  split_k<<<1024,256,0,stream>>>(sn,  wch, wcl, 4*NC*DL);

  // input projection + prompts -> out(fp32)+planes, slab slot0 planes
  mgemm<0,4><<<G,B,0,stream>>>(hh,hl, nullptr,nullptr, nullptr, iph,ipl,
      ipb, tp, out, outh,outl, slabh,slabl, DL, DL);

  int ptr = 1;
  for(int t=0;t<4;t++){
    int pt = 1 + 4*t;
    for(int n=0;n<4;n++){
      relmax_k<<<16,256,0,stream>>>(relc, msg, pt, n, top, cons);
      mgemm<1,0><<<G,B,0,stream>>>(outh,outl, slabh,slabl, top,
          rwh+(size_t)n*DL*1024, rwl+(size_t)n*DL*1024, rb+(size_t)n*DL,
          nullptr, nullptr, zh,zl, nullptr,nullptr, 1024, 512);
      mgemm<0,1><<<G,B,0,stream>>>(zh,zl, nullptr,nullptr, nullptr,
          wch+(size_t)n*NC*DL, wcl+(size_t)n*NC*DL, b2+(size_t)n*NC,
          nullptr, sn, nullptr,nullptr, nullptr,nullptr, 512, 512);
      codemax_k<<<1024,256,0,stream>>>(sn, idxb);
      mgemm<2,2><<<G,B,0,stream>>>(zh,zl, cbh+(size_t)n*NC*DS, cbl+(size_t)n*NC*DS, idxb,
          c1h+(size_t)n*DL*640, c1l+(size_t)n*DL*640, c1b+(size_t)n*DL,
          nullptr, nullptr, hh,hl, nullptr,nullptr, 640, 512);
      mgemm<0,3><<<G,B,0,stream>>>(hh,hl, nullptr,nullptr, nullptr,
          c2h+(size_t)n*DL*DL, c2l+(size_t)n*DL*DL, c2b+(size_t)n*DL,
          out, sn, nullptr,nullptr, nullptr,nullptr, 512, 512);
      mupdate_k<<<1024,256,0,stream>>>(sn, out, outh,outl, slabh,slabl, relc, idxb,
          cb+(size_t)n*NC*DS, qw, qb, act, cons, msg, t,
          (t<3)? ptr : -1, (n==3 && t<3)? (1+4*(t+1)) : -1);
      ptr++;
    }
  }
}

// Round 5
// 1305.161 us; speedup vs baseline: 2.8224x; 1.0120x over previous
//
#include <hip/hip_runtime.h>
#include <math.h>

namespace {

typedef _Float16 f16;
typedef __attribute__((ext_vector_type(8))) _Float16 f16x8;
typedef __attribute__((ext_vector_type(4))) float f32x4;

constexpr int TOK = 4096;
constexpr int DL  = 512;
constexpr int DS  = 128;
constexpr int NC  = 512;
constexpr int NSLOT = 13;

__device__ __forceinline__ float wsum(float v){
  #pragma unroll
  for(int o=32;o>0;o>>=1) v += __shfl_xor(v,o);
  return v;
}

__device__ __forceinline__ void gload16(const void* g, void* l){
  __builtin_amdgcn_global_load_lds(
      (const __attribute__((address_space(1))) unsigned int*)g,
      (__attribute__((address_space(3))) unsigned int*)l, 16, 0, 0);
}

// byte offset of the 16B slot holding (row, 16B-granule g) — bank-spread bijection
__device__ __forceinline__ int slotb(int row, int g){
  return (((row ^ ((row>>2)&1))<<2) | (g ^ (row&3))) << 4;
}

// ===========================================================================
// fp16x2-split MFMA GEMM, BM=64 BN=64 BK=32, 4 waves (each a 32x32 tile).
// Grid (64,8), 2 blocks/CU. 3-buffer pipeline with counted s_waitcnt vmcnt(4):
// stage kt+2 while computing kt; loads stay in flight across barriers.
// AMODE: 0 plain; 1 concat [A1 | slab[gidx[m]]]; 2 concat [A1 | cb[gsel[m]]]
//        where gsel is finalized IN-PROLOGUE from score partials (fused codemax).
// EPI: 0 planes (zread) ; 1 score block-partial argmax (no C write)
//      2 relu planes (hid) ; 3 fp32 + fp32-res (nodeo) ; 4 fp32+prompt+planes+slab0
// ===========================================================================
template<int AMODE,int EPI>
__global__ __launch_bounds__(256,2) void mgemm(
    const f16* __restrict__ A1h, const f16* __restrict__ A1l,
    const f16* __restrict__ A2h, const f16* __restrict__ A2l,
    const int* __restrict__ gidx,
    const f16* __restrict__ Bh, const f16* __restrict__ Bl,
    const float* __restrict__ bias, const float* __restrict__ res,
    float* __restrict__ Cf, f16* __restrict__ Ch, f16* __restrict__ Cl,
    f16* __restrict__ C2h, f16* __restrict__ C2l,
    float* __restrict__ scpv, int* __restrict__ scpi, int* __restrict__ idxg,
    int K, int K0)
{
  constexpr int SMB = 16384;  // Ah 4K | Al 4K | Bh 4K | Bl 4K
  __shared__ __align__(16) char smem[3*SMB];
  __shared__ int gsel[64];
  __shared__ float redv[4][32];
  __shared__ int   redi[4][32];
  const int tid = threadIdx.x, w = tid>>6, l = tid&63;
  const int m0 = blockIdx.x*64, n0 = blockIdx.y*64;
  const int NK = K>>5, SW = K0>>5;

  // ---- fused code-argmax finalize (reads 8 block-partials, ascending y) ----
  if(AMODE==2){
    if(tid<64){
      int m = m0+tid;
      float bv = -INFINITY; int bi = 0;
      #pragma unroll
      for(int y=0;y<8;y++){
        float v = scpv[(size_t)y*TOK + m];
        if(v > bv){ bv=v; bi=scpi[(size_t)y*TOK + m]; }
      }
      gsel[tid]=bi;
      idxg[m]=bi;                      // duplicate identical writes across y-blocks
    }
    __syncthreads();
  }

  // ---- staging setup: 16 chunks of 1KB per K-step; wave w owns [4w,4w+4) ---
  const f16* sp[4]; const f16* sp2[4]; int loff[4];
  #pragma unroll
  for(int i=0;i<4;i++){
    int c = 4*w+i;
    int isA = (c<8);
    int plane = isA ? (c>>2) : ((c-8)>>2);
    int cidx  = isA ? (c&3)  : ((c-8)&3);
    loff[i] = (isA?0:8192) + plane*4096 + cidx*1024;
    int s = (cidx<<6) + l;
    int rp = s>>2, row = rp ^ ((rp>>2)&1), g = (s&3) ^ (row&3);  // inverse slotb
    int g8 = g<<3;
    if(isA){
      int m = m0 + row;
      const f16* p1 = (plane? A1l : A1h) + ((size_t)m<<9) + g8;
      sp[i] = p1;
      if(AMODE==1)      sp2[i] = (plane? A2l : A2h) + ((size_t)gidx[m]<<21) + ((size_t)m<<9) + g8;
      else if(AMODE==2) sp2[i] = (plane? A2l : A2h) + ((size_t)gsel[row]<<7) + g8;
      else              sp2[i] = p1;
    } else {
      sp[i] = (plane? Bl : Bh) + (size_t)(n0+row)*K + g8;
      sp2[i] = sp[i];
    }
  }

  const int wr = w>>1, wc = w&1, q = l>>4, r = l&15;
  int aoff[2], boff[2];
  #pragma unroll
  for(int i=0;i<2;i++) aoff[i] = slotb(32*wr + 16*i + r, q);
  #pragma unroll
  for(int j=0;j<2;j++) boff[j] = 8192 + slotb(32*wc + 16*j + r, q);

  f32x4 acc1[2][2] = {}, acc2[2][2] = {};

  // advance staging pointers to step snext (handles part1->part2 switch)
  auto advance = [&](int snext){
    #pragma unroll
    for(int i=0;i<4;i++){
      if(AMODE!=0 && (4*w+i)<8 && snext==SW) sp[i] = sp2[i];
      else                                    sp[i] += 32;
    }
  };

  // ---- prologue: stage steps 0 and 1 (NK >= 16 always here) ----
  #pragma unroll
  for(int i=0;i<4;i++) gload16(sp[i], smem + loff[i]);
  advance(1);
  #pragma unroll
  for(int i=0;i<4;i++) gload16(sp[i], smem + SMB + loff[i]);
  advance(2);
  asm volatile("s_waitcnt vmcnt(4)" ::: "memory");   // step-0 loads done
  __builtin_amdgcn_s_barrier();

  int roff = 0, soff = 2*SMB;
  for(int kt=0; kt<NK; ++kt){
    const char* Lb = smem + roff;
    f16x8 ah[2], al[2], bh[2], bl[2];
    #pragma unroll
    for(int i=0;i<2;i++){
      ah[i] = *(const f16x8*)(Lb + aoff[i]);
      al[i] = *(const f16x8*)(Lb + 4096 + aoff[i]);
    }
    #pragma unroll
    for(int j=0;j<2;j++){
      bh[j] = *(const f16x8*)(Lb + boff[j]);
      bl[j] = *(const f16x8*)(Lb + 4096 + boff[j]);
    }
    if(kt+2 < NK){
      #pragma unroll
      for(int i=0;i<4;i++) gload16(sp[i], smem + soff + loff[i]);
      advance(kt+3);
    }
    #pragma unroll
    for(int i=0;i<2;i++)
      #pragma unroll
      for(int j=0;j<2;j++){
        acc1[i][j] = __builtin_amdgcn_mfma_f32_16x16x32_f16(ah[i], bh[j], acc1[i][j], 0,0,0);
        acc2[i][j] = __builtin_amdgcn_mfma_f32_16x16x32_f16(ah[i], bl[j], acc2[i][j], 0,0,0);
        acc2[i][j] = __builtin_amdgcn_mfma_f32_16x16x32_f16(al[i], bh[j], acc2[i][j], 0,0,0);
      }
    if(kt+2 < NK){
      // counted wait: step kt+1's loads (issued one iter ago) are done; the
      // 4 just-issued step-kt+2 loads stay in flight across the barrier.
      asm volatile("s_waitcnt vmcnt(4)" ::: "memory");
      __builtin_amdgcn_s_barrier();
    } else if(kt+1 < NK){
      asm volatile("s_waitcnt vmcnt(0)" ::: "memory");  // tail: drain last stage
      __builtin_amdgcn_s_barrier();
    }
    roff = (roff==2*SMB)? 0 : roff+SMB;
    soff = (soff==2*SMB)? 0 : soff+SMB;
  }

  if(EPI!=1){
    #pragma unroll
    for(int i=0;i<2;i++)
      #pragma unroll
      for(int j=0;j<2;j++)
        #pragma unroll
        for(int rr=0;rr<4;rr++){
          int rowm = m0 + 32*wr + 16*i + 4*q + rr;
          int coln = n0 + 32*wc + 16*j + r;
          size_t o = ((size_t)rowm<<9) + coln;
          float v = acc1[i][j][rr] + acc2[i][j][rr]*(1.0f/2048.0f) + bias[coln];
          if(EPI==2) v = fmaxf(v, 0.f);
          if(EPI==3) v += res[o];
          if(EPI==4) v += res[(((size_t)(rowm&255))<<9) + coln];
          if(EPI==3 || EPI==4) Cf[o] = v;
          if(EPI==0 || EPI==2 || EPI==4){
            f16 h = (f16)v;
            Ch[o] = h; Cl[o] = (f16)((v-(float)h)*2048.0f);
          }
          if(EPI==4){
            f16 h = (f16)v;
            C2h[o] = h; C2l[o] = (f16)((v-(float)h)*2048.0f);
          }
        }
  } else {
    // block-partial argmax over this block's 64 cols, exact first-index ties
    #pragma unroll
    for(int i=0;i<2;i++)
      #pragma unroll
      for(int rr=0;rr<4;rr++){
        float v0 = acc1[i][0][rr] + acc2[i][0][rr]*(1.0f/2048.0f) + bias[n0+32*wc+r];
        float v1 = acc1[i][1][rr] + acc2[i][1][rr]*(1.0f/2048.0f) + bias[n0+32*wc+16+r];
        float bv; int bc;
        if(v1 > v0){ bv=v1; bc=n0+32*wc+16+r; } else { bv=v0; bc=n0+32*wc+r; }
        #pragma unroll
        for(int o=1;o<16;o<<=1){
          float ov = __shfl_xor(bv,o); int oi = __shfl_xor(bc,o);
          if(ov>bv || (ov==bv && oi<bc)){ bv=ov; bc=oi; }
        }
        if(r==0){ redv[w][16*i+4*q+rr]=bv; redi[w][16*i+4*q+rr]=bc; }
      }
    __syncthreads();
    if(tid<64){
      int wr2 = tid>>5, li = tid&31;
      float bv = redv[2*wr2][li]; int bc = redi[2*wr2][li];
      float ov = redv[2*wr2+1][li]; int oi = redi[2*wr2+1][li];
      if(ov>bv || (ov==bv && oi<bc)){ bv=ov; bc=oi; }
      scpv[(size_t)blockIdx.y*TOK + m0 + tid] = bv;
      scpi[(size_t)blockIdx.y*TOK + m0 + tid] = bc;
    }
  }
}

// --- fp32 -> (hi, lo*2048) split -------------------------------------------
__global__ void split_k(const float* __restrict__ src, f16* __restrict__ hi,
                        f16* __restrict__ lo, int n){
  for(int i = blockIdx.x*256 + threadIdx.x; i < n; i += gridDim.x*256){
    float v = src[i];
    f16 h = (f16)v;
    hi[i] = h;
    lo[i] = (f16)((v - (float)h)*2048.0f);
  }
}

// --- wcomb[n*512+c][l] = sum_d cb[n][c][d] * sym_w[n][d][l]  (fp32, small) --
__global__ __launch_bounds__(256)
void wcomb_k(const float* __restrict__ A, const float* __restrict__ Wall,
             float* __restrict__ C)
{
  constexpr int T=256;
  __shared__ float As[32][68];
  __shared__ float Ws[32][132];
  const int tid = threadIdx.x;
  const int m0 = blockIdx.x*64, n0 = blockIdx.y*128;
  const float* W = Wall + (size_t)(m0>>9)*DS*DL;
  const int ty = tid>>4, tx = tid&15;
  float4 pa[2], pw[4];
  auto loadA = [&](int k0){
    #pragma unroll
    for(int it=0; it<2; ++it){
      int v = tid + T*it; int rr = v>>3, c4 = v&7;
      pa[it] = *(const float4*)(A + (size_t)(m0+rr)*DS + k0 + (c4<<2));
    }
  };
  auto loadW = [&](int k0){
    #pragma unroll
    for(int it=0; it<4; ++it){
      int v = tid + T*it; int rr = v>>5, c4 = v&31;
      pw[it] = *(const float4*)(W + (size_t)(k0+rr)*DL + n0 + (c4<<2));
    }
  };
  float acc[4][8];
  #pragma unroll
  for(int i=0;i<4;i++)
    #pragma unroll
    for(int j=0;j<8;j++) acc[i][j]=0.f;
  loadA(0); loadW(0);
  for(int k0=0; k0<DS; k0+=32){
    __syncthreads();
    #pragma unroll
    for(int it=0; it<2; ++it){
      int v = tid + T*it; int rr=v>>3, c4=v&7;
      As[(c4<<2)+0][rr]=pa[it].x; As[(c4<<2)+1][rr]=pa[it].y;
      As[(c4<<2)+2][rr]=pa[it].z; As[(c4<<2)+3][rr]=pa[it].w;
    }
    #pragma unroll
    for(int it=0; it<4; ++it){
      int v = tid + T*it; int rr=v>>5, c4=v&31;
      *(float4*)&Ws[rr][c4<<2] = pw[it];
    }
    __syncthreads();
    if(k0+32 < DS){ loadA(k0+32); loadW(k0+32); }
    #pragma unroll
    for(int kk=0; kk<32; kk++){
      float4 a4 = *(const float4*)&As[kk][ty<<2];
      float4 b0 = *(const float4*)&Ws[kk][tx<<2];
      float4 b1 = *(const float4*)&Ws[kk][64+(tx<<2)];
      float a[4]={a4.x,a4.y,a4.z,a4.w};
      float b[8]={b0.x,b0.y,b0.z,b0.w,b1.x,b1.y,b1.z,b1.w};
      #pragma unroll
      for(int i=0;i<4;i++)
        #pragma unroll
        for(int j=0;j<8;j++) acc[i][j] = fmaf(a[i], b[j], acc[i][j]);
    }
  }
  #pragma unroll
  for(int i=0;i<4;i++){
    int m = m0 + (ty<<2) + i;
    #pragma unroll
    for(int j=0;j<8;j++){
      int n = n0 + ((j<4)? (tx<<2)+j : 64+(tx<<2)+(j-4));
      C[((size_t)m<<9)+n] = acc[i][j];
    }
  }
}

// --- init: active=1, msg={1,0..}, cons=0, relc slot0 = qry_b ---------------
__global__ void init_k(int* __restrict__ msg, int* __restrict__ act,
                       float* __restrict__ relc, const float* __restrict__ qb,
                       int* __restrict__ cons){
  int i = blockIdx.x*256 + threadIdx.x;
  if(i < TOK){
    act[i] = 1;
    #pragma unroll
    for(int nn=0;nn<4;nn++) relc[nn*TOK + i] = qb[nn];
  }
  if(i < 32){ msg[i] = (i==0) ? 1 : 0; cons[i] = 0; }
}

// --- combined quantizer bias: b2 = sym_b.cb - 0.5|cb|^2 --------------------
__global__ void bias2_k(const float* __restrict__ cb, const float* __restrict__ sb,
                        float* __restrict__ b2){
  int row = blockIdx.x*4 + (threadIdx.x>>6);
  int lane = threadIdx.x&63;
  const float* cv = cb + ((size_t)row<<7);
  const float* sbn = sb + ((row>>9)<<7);
  float c0=cv[lane], c1=cv[lane+64];
  float nrm = c0*c0 + c1*c1;
  float dt  = c0*sbn[lane] + c1*sbn[lane+64];
  nrm = wsum(nrm); dt = wsum(dt);
  if(lane==0) b2[row] = dt - 0.5f*nrm;
}

// --- per-token bus argmax (msg is the live snapshot during an op) ----------
__global__ void relmax_k(const float* __restrict__ relc, const int* __restrict__ msg,
                         int pt, int node, int* __restrict__ top, int* __restrict__ cons){
  int tok = blockIdx.x*256 + threadIdx.x;
  float best = -1e9f; int bs = 0;
  for(int s=0;s<pt;s++){
    float v = msg[s] ? relc[(size_t)((s<<2)+node)*TOK + tok] : -1e9f;
    if(v > best){ best = v; bs = s; }
  }
  top[tok] = bs;
  cons[bs] = 1;
}

// --- halting / update / append / rel-cache / mask-fold ---------------------
__global__ void mupdate_k(const float* __restrict__ no_, float* __restrict__ out,
                          f16* __restrict__ outh, f16* __restrict__ outl,
                          f16* __restrict__ slabh, f16* __restrict__ slabl,
                          float* __restrict__ relc, const int* __restrict__ idx,
                          const float* __restrict__ cbn, const float* __restrict__ qw,
                          const float* __restrict__ qb, int* __restrict__ act,
                          int* __restrict__ cons, int* __restrict__ msg,
                          int t, int ptr, int pe){
  int m = blockIdx.x*4 + (threadIdx.x>>6);
  int lane = threadIdx.x&63;
  const float* nrow = no_ + ((size_t)m<<9);
  float* orow = out + ((size_t)m<<9);
  float nv[8]; float s=0.f;
  #pragma unroll
  for(int rr=0;rr<8;rr++){
    int c = lane + (rr<<6);
    nv[rr]=nrow[c];
    float d = nv[rr]-orow[c]; s += d*d;
  }
  s = wsum(s);
  float delta = sqrtf(s);
  int a = act[m];
  int halt = (delta < 1e-3f) && a;
  int assigned = (t>0) ? a : 1;
  int upd = assigned && !halt;
  if(lane==0) act[m] = a && !halt;
  if(upd){
    #pragma unroll
    for(int rr=0;rr<8;rr++){
      int c = lane + (rr<<6);
      float v = nv[rr];
      orow[c] = v;
      f16 h = (f16)v;
      outh[((size_t)m<<9)+c] = h;
      outl[((size_t)m<<9)+c] = (f16)((v-(float)h)*2048.0f);
    }
  }
  if(ptr >= 0){
    size_t so = (((size_t)ptr)<<21) + ((size_t)m<<9);
    #pragma unroll
    for(int rr=0;rr<8;rr++){
      int c = lane + (rr<<6);
      float v = nv[rr];
      f16 h = (f16)v;
      slabh[so+c] = h;
      slabl[so+c] = (f16)((v-(float)h)*2048.0f);
    }
    const float* qv = cbn + ((size_t)idx[m]<<7);
    float q0=qv[lane], q1=qv[lane+64];
    #pragma unroll
    for(int nn=0;nn<4;nn++){
      float pr = q0*qw[(nn<<7)+lane] + q1*qw[(nn<<7)+64+lane];
      pr = wsum(pr);
      if(lane==0) relc[(size_t)((ptr<<2)+nn)*TOK + m] = pr + qb[nn];
    }
  }
  if(pe >= 0 && blockIdx.x==0 && threadIdx.x < 32){
    int s2 = threadIdx.x;
    msg[s2] = (s2 < pe) && !cons[s2];
    cons[s2] = 0;
  }
}

} // namespace

extern "C" void kernel_launch(void* const* d_in, const int* in_sizes, int n_in,
                              void* d_out, int out_size, void* d_ws, size_t ws_size,
                              hipStream_t stream)
{
  (void)in_sizes; (void)n_in; (void)out_size; (void)ws_size;
  const float* x   = (const float*)d_in[0];
  const float* ipw = (const float*)d_in[1];
  const float* ipb = (const float*)d_in[2];
  const float* tp  = (const float*)d_in[3];
  const float* sw  = (const float*)d_in[4];
  const float* sb  = (const float*)d_in[5];
  const float* qw  = (const float*)d_in[6];
  const float* qb  = (const float*)d_in[7];
  const float* rw  = (const float*)d_in[8];
  const float* rb  = (const float*)d_in[9];
  const float* c1w = (const float*)d_in[10];
  const float* c1b = (const float*)d_in[11];
  const float* c2w = (const float*)d_in[12];
  const float* c2b = (const float*)d_in[13];
  const float* cb  = (const float*)d_in[14];
  float* out = (float*)d_out;

  char* p = (char*)d_ws;
  auto alloc = [&](size_t b)->char*{ char* r=p; p += (b+255)&~(size_t)255; return r; };
  f16* slabh = (f16*)alloc((size_t)NSLOT*TOK*DL*2);
  f16* slabl = (f16*)alloc((size_t)NSLOT*TOK*DL*2);
  f16* outh  = (f16*)alloc((size_t)TOK*DL*2);
  f16* outl  = (f16*)alloc((size_t)TOK*DL*2);
  f16* zh    = (f16*)alloc((size_t)TOK*DL*2);
  f16* zl    = (f16*)alloc((size_t)TOK*DL*2);
  f16* hh    = (f16*)alloc((size_t)TOK*DL*2);
  f16* hl    = (f16*)alloc((size_t)TOK*DL*2);
  float* sn  = (float*)alloc((size_t)TOK*DL*4);      // nodeo fp32 + wcomb staging
  f16* rwh   = (f16*)alloc((size_t)4*DL*1024*2);
  f16* rwl   = (f16*)alloc((size_t)4*DL*1024*2);
  f16* c1h   = (f16*)alloc((size_t)4*DL*640*2);
  f16* c1l   = (f16*)alloc((size_t)4*DL*640*2);
  f16* c2h   = (f16*)alloc((size_t)4*DL*DL*2);
  f16* c2l   = (f16*)alloc((size_t)4*DL*DL*2);
  f16* wch   = (f16*)alloc((size_t)4*NC*DL*2);
  f16* wcl   = (f16*)alloc((size_t)4*NC*DL*2);
  f16* iph   = (f16*)alloc((size_t)DL*DL*2);
  f16* ipl   = (f16*)alloc((size_t)DL*DL*2);
  f16* cbh   = (f16*)alloc((size_t)4*NC*DS*2);
  f16* cbl   = (f16*)alloc((size_t)4*NC*DS*2);
  float* b2  = (float*)alloc(4*NC*4);
  float* relc= (float*)alloc((size_t)NSLOT*4*TOK*4);
  float* scpv= (float*)alloc((size_t)8*TOK*4);
  int* scpi  = (int*)alloc((size_t)8*TOK*4);
  int* top   = (int*)alloc(TOK*4);
  int* idxb  = (int*)alloc(TOK*4);
  int* act   = (int*)alloc(TOK*4);
  int* msg   = (int*)alloc(256);
  int* cons  = (int*)alloc(256);

  dim3 G(64,8), B(256);

  init_k<<<16,256,0,stream>>>(msg, act, relc, qb, cons);
  bias2_k<<<512,256,0,stream>>>(cb, sb, b2);
  wcomb_k<<<dim3(32,4),B,0,stream>>>(cb, sw, sn);
  split_k<<<2048,256,0,stream>>>(x,   hh,  hl,  TOK*DL);   // x planes staged in hh/hl
  split_k<<<512 ,256,0,stream>>>(ipw, iph, ipl, DL*DL);
  split_k<<<2048,256,0,stream>>>(rw,  rwh, rwl, 4*DL*1024);
  split_k<<<2048,256,0,stream>>>(c1w, c1h, c1l, 4*DL*640);
  split_k<<<1024,256,0,stream>>>(c2w, c2h, c2l, 4*DL*DL);
  split_k<<<512 ,256,0,stream>>>(cb,  cbh, cbl, 4*NC*DS);
  split_k<<<1024,256,0,stream>>>(sn,  wch, wcl, 4*NC*DL);

  // input projection + prompts -> out(fp32)+planes, slab slot0 planes
  mgemm<0,4><<<G,B,0,stream>>>(hh,hl, nullptr,nullptr, nullptr, iph,ipl,
      ipb, tp, out, outh,outl, slabh,slabl, nullptr,nullptr,nullptr, DL, DL);

  int ptr = 1;
  for(int t=0;t<4;t++){
    int pt = 1 + 4*t;
    for(int n=0;n<4;n++){
      relmax_k<<<16,256,0,stream>>>(relc, msg, pt, n, top, cons);
      // z_read = [out | slab[top]] @ read_w^T + read_b
      mgemm<1,0><<<G,B,0,stream>>>(outh,outl, slabh,slabl, top,
          rwh+(size_t)n*DL*1024, rwl+(size_t)n*DL*1024, rb+(size_t)n*DL,
          nullptr, nullptr, zh,zl, nullptr,nullptr, nullptr,nullptr,nullptr, 1024, 512);
      // scores -> block-partial argmax (fused codemax part 1)
      mgemm<0,1><<<G,B,0,stream>>>(zh,zl, nullptr,nullptr, nullptr,
          wch+(size_t)n*NC*DL, wcl+(size_t)n*NC*DL, b2+(size_t)n*NC,
          nullptr, nullptr, nullptr,nullptr, nullptr,nullptr, scpv,scpi,nullptr, 512, 512);
      // hid = relu([z_read | cb[idx]] @ c1_w^T + c1_b)  (fused codemax finalize)
      mgemm<2,2><<<G,B,0,stream>>>(zh,zl, cbh+(size_t)n*NC*DS, cbl+(size_t)n*NC*DS, nullptr,
          c1h+(size_t)n*DL*640, c1l+(size_t)n*DL*640, c1b+(size_t)n*DL,
          nullptr, nullptr, hh,hl, nullptr,nullptr, scpv,scpi,idxb, 640, 512);
      // node_out = hid @ c2_w^T + c2_b + out
      mgemm<0,3><<<G,B,0,stream>>>(hh,hl, nullptr,nullptr, nullptr,
          c2h+(size_t)n*DL*DL, c2l+(size_t)n*DL*DL, c2b+(size_t)n*DL,
          out, sn, nullptr,nullptr, nullptr,nullptr, nullptr,nullptr,nullptr, 512, 512);
      // halting / selective update / bus append / rel cache / mask fold
      mupdate_k<<<1024,256,0,stream>>>(sn, out, outh,outl, slabh,slabl, relc, idxb,
          cb+(size_t)n*NC*DS, qw, qb, act, cons, msg, t,
          (t<3)? ptr : -1, (n==3 && t<3)? (1+4*(t+1)) : -1);
      ptr++;
    }
  }
}